// Round 6
// baseline (156.622 us; speedup 1.0000x reference)
//
#include <hip/hip_runtime.h>
#include <stdint.h>

#define B 8
#define F 8192
#define C 256
#define K 4
#define P (F / 4)     // 2048
#define CAP 16        // max tracked incoming collapsed faces per target
#define NB 4096       // linear bins over per-batch [lo, hi]
#define BF (B * F)
#define CCAP 1024     // leader LDS candidate capacity (bin==T pop ~ O(10))

typedef float f32x4 __attribute__((ext_vector_type(4)));

// Monotone, deterministic linear bin — identical expression in every block.
__device__ __forceinline__ int binOf(float v, float lo, float scale) {
    int bin = (int)((v - lo) * scale);
    return bin < 0 ? 0 : (bin > NB - 1 ? NB - 1 : bin);
}

// ---------------------------------------------------------------------------
// kW: one wave per face — gather K=4 ring rows, mean, L2 norm^2 -> w.
// (sqrt dropped: monotone — validated r4/r5.) Lane 0 zeroes cnt/flag.
// Block->batch swizzle: blockIdx&7 = batch == XCD.
// ---------------------------------------------------------------------------
__global__ __launch_bounds__(256) void kW(const float* __restrict__ feat,
                                          const int* __restrict__ ring,
                                          float* __restrict__ w,
                                          int* __restrict__ cnt,
                                          int* __restrict__ flag) {
    const int b     = blockIdx.x & 7;                       // batch == XCD
    const int inner = blockIdx.x >> 3;                      // [0, 2048)
    const int wid   = b * F + inner * 4 + (threadIdx.x >> 6);
    const int lane  = threadIdx.x & 63;

    const int rbase = wid * K;
    const int r0 = ring[rbase + 0], r1 = ring[rbase + 1];
    const int r2 = ring[rbase + 2], r3 = ring[rbase + 3];
    const float4* f4 = (const float4*)feat;
    const size_t base = (size_t)b * F;
    const int    CW   = C / 4;
    const float4 v0 = f4[(base + r0) * CW + lane];
    const float4 v1 = f4[(base + r1) * CW + lane];
    const float4 v2 = f4[(base + r2) * CW + lane];
    const float4 v3 = f4[(base + r3) * CW + lane];

    float4 a;
    a.x = (v0.x + v1.x) + (v2.x + v3.x);
    a.y = (v0.y + v1.y) + (v2.y + v3.y);
    a.z = (v0.z + v1.z) + (v2.z + v3.z);
    a.w = (v0.w + v1.w) + (v2.w + v3.w);
    float s = (a.x * a.x + a.y * a.y + a.z * a.z + a.w * a.w) * 0.0625f;
#pragma unroll
    for (int off = 32; off > 0; off >>= 1) s += __shfl_down(s, off, 64);
    if (lane == 0) {
        w[wid]    = s;                                      // norm^2 (monotone)
        cnt[wid]  = 0;
        flag[wid] = 0;
    }
}

// ---------------------------------------------------------------------------
// kFS: fused threshold + scatter + boundary-select. 256 blocks x 256 thr;
// block g owns faces [g*256, g*256+256) of batch b = g>>5, BUT reads its
// batch's FULL w slice (32 vals/thread, registers; 32 KB L2-shared by the
// batch's 32 blocks) and redundantly recomputes min/max + histogram + scan
// -> (T, R). Bit-deterministic across blocks: fp min/max are exact,
// hist/scan are integer, binOf identical. Then:
//   - every block: scatter its own 256 faces (bin<T -> flag + 3 pushes)
//     at FULL GPU width (round-2 lesson);
//   - leader block (g%32==0): compact bin==T candidates from registers,
//     O(n^2) exact rank (n ~ O(10)), rank<R -> flag + push (old kSel).
// Kills the kHT dispatch + boundary; no lsb/tbin/cand/ccnt globals at all;
// no fences (round-3 lesson).
// ---------------------------------------------------------------------------
__global__ __launch_bounds__(256) void kFS(const float* __restrict__ w,
                                           const int* __restrict__ adj,
                                           int* __restrict__ flag,
                                           int* __restrict__ cnt,
                                           int* __restrict__ srcs) {
    __shared__ int h[NB];                                   // 16 KiB
    __shared__ unsigned long long carr[CCAP];               // 8 KiB
    __shared__ unsigned int redmn[4], redmx[4];
    __shared__ int wsum[4];
    __shared__ unsigned int slo, shi;
    __shared__ int sT, sR, scnt;
    const int g    = blockIdx.x;
    const int b    = g >> 5;                                // batch
    const int gg   = g & 31;                                // block-in-batch
    const int t    = threadIdx.x;
    const int lane = t & 63, wv = t >> 6;

    if (t == 0) scnt = 0;
    for (int i = t; i < NB; i += 256) h[i] = 0;

    // full batch into registers: val[k] = w[b*F + k*256 + t] (coalesced)
    float val[32];
    unsigned int mn = 0xFFFFFFFFu, mx = 0u;
#pragma unroll
    for (int k = 0; k < 32; ++k) {
        val[k] = w[b * F + k * 256 + t];
        const unsigned int u = __float_as_uint(val[k]);     // w>=0: bit-monotone
        mn = mn < u ? mn : u;
        mx = mx > u ? mx : u;
    }
#pragma unroll
    for (int off = 32; off > 0; off >>= 1) {
        const unsigned int o1 = __shfl_xor(mn, off, 64); mn = mn < o1 ? mn : o1;
        const unsigned int o2 = __shfl_xor(mx, off, 64); mx = mx > o2 ? mx : o2;
    }
    if (lane == 0) { redmn[wv] = mn; redmx[wv] = mx; }
    __syncthreads();                                        // [1] h zeroed + partials
    if (t == 0) {
        unsigned int a = redmn[0], c = redmx[0];
        for (int i = 1; i < 4; ++i) {
            a = a < redmn[i] ? a : redmn[i];
            c = c > redmx[i] ? c : redmx[i];
        }
        slo = a; shi = c;
    }
    __syncthreads();                                        // [2]
    const float lo    = __uint_as_float(slo);
    const float hi    = __uint_as_float(shi);
    const float scale = (float)(NB - 2) / fmaxf(hi - lo, 1e-30f);

    // histogram (avg ~2 hits/bin -> negligible LDS-atomic contention)
#pragma unroll
    for (int k = 0; k < 32; ++k) atomicAdd(&h[binOf(val[k], lo, scale)], 1);
    __syncthreads();                                        // [3]

    // scan: 16 bins/thread serial sum -> wave shfl scan -> cross-wave combine
    int s = 0;
#pragma unroll
    for (int i = 0; i < 16; ++i) s += h[t * 16 + i];
    int incl = s;
#pragma unroll
    for (int off = 1; off < 64; off <<= 1) {
        const int u = __shfl_up(incl, off, 64);
        if (lane >= off) incl += u;
    }
    if (lane == 63) wsum[wv] = incl;
    __syncthreads();                                        // [4]
    int add = 0;
    for (int i = 0; i < wv; ++i) add += wsum[i];
    const int inclT = incl + add;
    const int exclT = inclT - s;
    if (P - 1 >= exclT && P - 1 < inclT) {                  // exactly one thread
        int c = exclT;
#pragma unroll
        for (int i = 0; i < 16; ++i) {
            const int bin = t * 16 + i;
            const int hv  = h[bin];
            if (P - 1 < c + hv) { sT = bin; sR = P - c; break; }
            c += hv;
        }
    }
    __syncthreads();                                        // [5]
    const int T = sT, R = sR;

    // ---- scatter own 256 faces (full-width phase) ----
    const float myv = val[gg];
    const int face  = b * F + gg * 256 + t;
    if (binOf(myv, lo, scale) < T) {
        flag[face] = 1;
#pragma unroll
        for (int j = 0; j < 3; ++j) {
            const int n    = adj[(size_t)face * 3 + j];
            const int tgt  = b * F + n;
            const int slot = atomicAdd(&cnt[tgt], 1);
            if (slot < CAP) srcs[(size_t)tgt * CAP + slot] = face;
        }
    }

    // ---- leader block: boundary-bin exact rank (old kSel) ----
    if (gg == 0) {                                          // block-uniform branch
#pragma unroll
        for (int k = 0; k < 32; ++k) {
            if (binOf(val[k], lo, scale) == T) {
                const int pos = atomicAdd(&scnt, 1);        // LDS atomic
                if (pos < CCAP)
                    carr[pos] = ((unsigned long long)__float_as_uint(val[k]) << 32) |
                                (uint32_t)(k * 256 + t);    // idx in [0,F)
            }
        }
        __syncthreads();                                    // leader-only: uniform
        const int n = scnt < CCAP ? scnt : CCAP;
        for (int i = t; i < n; i += 256) {
            const unsigned long long my = carr[i];
            int rank = 0;
            for (int j = 0; j < n; ++j) rank += (carr[j] < my) ? 1 : 0;
            if (rank < R) {                                 // keys distinct (idx bits)
                const int tt = b * F + (int)(uint32_t)my;
                flag[tt] = 1;
#pragma unroll
                for (int j = 0; j < 3; ++j) {
                    const int nb   = adj[(size_t)tt * 3 + j];
                    const int tgt  = b * F + nb;
                    const int slot = atomicAdd(&cnt[tgt], 1);
                    if (slot < CAP) srcs[(size_t)tgt * CAP + slot] = tt;
                }
            }
        }
    }
}

// ---------------------------------------------------------------------------
// kG: one wave per face — fused merge + normalize + erase; NT stores for the
// streaming 64 MB output (round-5). NEW: srcs row loaded only when the wave
// actually has incoming sources (mm>0, wave-uniform; ~47% of faces skip).
// ---------------------------------------------------------------------------
__global__ __launch_bounds__(256) void kG(const float* __restrict__ feat,
                                          const int* __restrict__ cnt,
                                          const int* __restrict__ flag,
                                          const int* __restrict__ srcs,
                                          float* __restrict__ out) {
    const int b     = blockIdx.x & 7;                       // batch == XCD
    const int inner = blockIdx.x >> 3;
    const int wid   = b * F + inner * 4 + (threadIdx.x >> 6);
    const int lane  = threadIdx.x & 63;
    f32x4* drow = (f32x4*)(out + (size_t)wid * C);

    if (flag[wid]) {                                        // wave-uniform branch
        f32x4 z = {0.f, 0.f, 0.f, 0.f};
        __builtin_nontemporal_store(z, &drow[lane]);
        return;
    }
    const int m  = cnt[wid];
    const int mm = m < CAP ? m : CAP;

    float4 acc = ((const float4*)(feat + (size_t)wid * C))[lane];
    if (mm > 0) {                                           // wave-uniform
        const int sidx = (lane < CAP) ? srcs[(size_t)wid * CAP + lane] : 0;
        const float inv3 = 1.0f / 3.0f;
        for (int i = 0; i < mm; ++i) {
            const int s = __shfl(sidx, i, 64);
            const float4 v = ((const float4*)(feat + (size_t)s * C))[lane];
            acc.x += v.x * inv3; acc.y += v.y * inv3;
            acc.z += v.z * inv3; acc.w += v.w * inv3;
        }
    }
    const float inv = 1.0f / (1.0f + (float)m);
    f32x4 r;
    r.x = acc.x * inv; r.y = acc.y * inv;
    r.z = acc.z * inv; r.w = acc.w * inv;
    __builtin_nontemporal_store(r, &drow[lane]);
}

extern "C" void kernel_launch(void* const* d_in, const int* in_sizes, int n_in,
                              void* d_out, int out_size, void* d_ws, size_t ws_size,
                              hipStream_t stream) {
    const float* feat = (const float*)d_in[0];
    const int*   adj  = (const int*)d_in[1];
    const int*   ring = (const int*)d_in[2];
    float* out = (float*)d_out;

    // ws layout: w | cnt | flag | srcs
    float* w    = (float*)d_ws;                             // B*F
    int*   cnt  = (int*)(w + BF);                           // B*F
    int*   flag = cnt + BF;                                 // B*F
    int*   srcs = flag + BF;                                // B*F*CAP (4 MiB)

    kW  <<<BF / 4, 256, 0, stream>>>(feat, ring, w, cnt, flag);
    kFS <<<BF / 256, 256, 0, stream>>>(w, adj, flag, cnt, srcs);
    kG  <<<BF / 4, 256, 0, stream>>>(feat, cnt, flag, srcs, out);
}